// Round 2
// baseline (665.204 us; speedup 1.0000x reference)
//
#include <hip/hip_runtime.h>

// ---------------------------------------------------------------------------
// GCN 2-layer fused pipeline for MI355X (gfx950)
//   h1 = relu(Dinv (A+I) Dinv (x@W1) + b1)
//   out = 0.5*(h1@Wc + bc) + 0.5*((alpha*h2 + (1-alpha)*h1)@Wf + bf)
//   h2 = relu(Dinv (A+I) Dinv (h1@W2) + b2)
// Strategy: per-call CSR build (hist/scan/fill), bf16 MFMA GEMMs (no fp32
// MFMA on CDNA4), bf16 storage of xw/h1 to halve gather bytes, node-per-wave
// aggregation with zero fp32 atomics, fused epilogues.
// R1 fix: edge_index arrives as int32 (harness converts integer inputs to
// int), NOT int64 — previous long long cast read past the buffer -> abort.
// ---------------------------------------------------------------------------

#define HID 128

typedef __bf16 bf16x8 __attribute__((ext_vector_type(8)));
typedef float  f32x4  __attribute__((ext_vector_type(4)));

__device__ __forceinline__ unsigned short f2bf(float x) {
    unsigned int b = __float_as_uint(x);
    b += 0x7fffu + ((b >> 16) & 1u);     // round-to-nearest-even
    return (unsigned short)(b >> 16);
}
__device__ __forceinline__ float bflo(unsigned int u) { return __uint_as_float(u << 16); }
__device__ __forceinline__ float bfhi(unsigned int u) { return __uint_as_float(u & 0xffff0000u); }

// --------------------------- CSR build helpers -----------------------------

__global__ void hist_kernel(const int* __restrict__ dst, int* __restrict__ counts,
                            int E, int n) {
    int e = blockIdx.x * 256 + threadIdx.x;
    if (e < E) {
        unsigned d = (unsigned)dst[e];
        if (d < (unsigned)n) atomicAdd(&counts[d], 1);
    }
}

__global__ void dinv_kernel(const int* __restrict__ counts, float* __restrict__ dinv, int n) {
    int i = blockIdx.x * 256 + threadIdx.x;
    if (i < n) dinv[i] = rsqrtf((float)(counts[i] + 1));   // +1 self-loop; deg>0 always
}

__global__ __launch_bounds__(256)
void scan1_kernel(const int* __restrict__ counts, int* __restrict__ rowp1,
                  int* __restrict__ partials, int n) {
    __shared__ int sh[256];
    const int t = threadIdx.x;
    const int base = blockIdx.x * 1024 + t * 4;
    int v0 = (base     < n) ? counts[base]     : 0;
    int v1 = (base + 1 < n) ? counts[base + 1] : 0;
    int v2 = (base + 2 < n) ? counts[base + 2] : 0;
    int v3 = (base + 3 < n) ? counts[base + 3] : 0;
    v1 += v0; v2 += v1; v3 += v2;
    sh[t] = v3;
    __syncthreads();
    for (int off = 1; off < 256; off <<= 1) {
        int x = (t >= off) ? sh[t - off] : 0;
        __syncthreads();
        sh[t] += x;
        __syncthreads();
    }
    const int prefix = sh[t] - v3;   // exclusive within block
    if (base     < n) rowp1[base]     = prefix + v0;
    if (base + 1 < n) rowp1[base + 1] = prefix + v1;
    if (base + 2 < n) rowp1[base + 2] = prefix + v2;
    if (base + 3 < n) rowp1[base + 3] = prefix + v3;
    if (t == 255) partials[blockIdx.x] = sh[255];
}

__global__ void scan2_kernel(int* partials, int nchunks) {
    if (threadIdx.x == 0 && blockIdx.x == 0) {
        int run = 0;
        for (int i = 0; i < nchunks; ++i) { int t = partials[i]; partials[i] = run; run += t; }
    }
}

__global__ void scan3_kernel(int* __restrict__ rowp, const int* __restrict__ partials, int n) {
    int i = blockIdx.x * 256 + threadIdx.x;
    if (i < n) rowp[1 + i] += partials[i >> 10];
    if (i == 0) rowp[0] = 0;
}

__global__ void rowcur_kernel(const int* __restrict__ rowp, int* __restrict__ rowcur, int n) {
    int i = blockIdx.x * 256 + threadIdx.x;
    if (i < n) rowcur[i] = rowp[i];
}

__global__ void fill_kernel(const int* __restrict__ src, const int* __restrict__ dst,
                            int* __restrict__ rowcur, int* __restrict__ colv,
                            int E, int n) {
    int e = blockIdx.x * 256 + threadIdx.x;
    if (e < E) {
        unsigned d = (unsigned)dst[e];
        if (d < (unsigned)n) {
            int pos = atomicAdd(&rowcur[d], 1);
            colv[pos] = src[e];
        }
    }
}

// W (K x 128, row-major fp32) -> Wt (128 x K, bf16) so B-frags are contiguous
__global__ void wtprep_kernel(const float* __restrict__ W, unsigned short* __restrict__ Wt, int K) {
    int idx = blockIdx.x * 256 + threadIdx.x;
    if (idx < 128 * K) {
        int nn = idx / K, k = idx - nn * K;
        Wt[(size_t)nn * K + k] = f2bf(W[(size_t)k * 128 + nn]);
    }
}

// ------------------------------- GEMM --------------------------------------
// Out[row][col] (bf16, N x 128) = A (N x K) @ W (K x 128), via Wt[col][k].
// Block: 256 thr = 4 waves, 128 rows x 128 cols. Per wave: 32 rows.
// MFMA 16x16x32 bf16 layouts (HW-verified per guide):
//   A: m=lane&15, k=(lane>>4)*8+j    B: n=lane&15, k=(lane>>4)*8+j
//   C/D: col=lane&15, row=(lane>>4)*4+v
template <bool A_BF16>
__global__ __launch_bounds__(256)
void gemm_kernel(const void* __restrict__ Aptr, const unsigned short* __restrict__ Wt,
                 unsigned short* __restrict__ Out, int nrows, int K) {
    const int tid  = threadIdx.x;
    const int wave = tid >> 6;
    const int lane = tid & 63;
    const int q = lane >> 4;
    const int r = lane & 15;
    const int wrow = blockIdx.x * 128 + wave * 32;

    f32x4 acc[2][8];
#pragma unroll
    for (int s = 0; s < 2; ++s)
#pragma unroll
        for (int c = 0; c < 8; ++c) acc[s][c] = (f32x4){0.f, 0.f, 0.f, 0.f};

    for (int k0 = 0; k0 < K; k0 += 32) {
        const int kk = k0 + q * 8;
        bf16x8 afrag[2];
#pragma unroll
        for (int s = 0; s < 2; ++s) {
            const int row = wrow + s * 16 + r;
            if (row < nrows) {
                if (A_BF16) {
                    afrag[s] = *reinterpret_cast<const bf16x8*>(
                        reinterpret_cast<const unsigned short*>(Aptr) + (size_t)row * K + kk);
                } else {
                    const float* ap = reinterpret_cast<const float*>(Aptr) + (size_t)row * K + kk;
                    const float4 x0 = *reinterpret_cast<const float4*>(ap);
                    const float4 x1 = *reinterpret_cast<const float4*>(ap + 4);
                    bf16x8 a;
                    a[0] = (__bf16)x0.x; a[1] = (__bf16)x0.y; a[2] = (__bf16)x0.z; a[3] = (__bf16)x0.w;
                    a[4] = (__bf16)x1.x; a[5] = (__bf16)x1.y; a[6] = (__bf16)x1.z; a[7] = (__bf16)x1.w;
                    afrag[s] = a;
                }
            } else {
                bf16x8 a;
#pragma unroll
                for (int j = 0; j < 8; ++j) a[j] = (__bf16)0.f;
                afrag[s] = a;
            }
        }
#pragma unroll
        for (int c = 0; c < 8; ++c) {
            const bf16x8 b = *reinterpret_cast<const bf16x8*>(Wt + (size_t)(c * 16 + r) * K + kk);
#pragma unroll
            for (int s = 0; s < 2; ++s)
                acc[s][c] = __builtin_amdgcn_mfma_f32_16x16x32_bf16(afrag[s], b, acc[s][c], 0, 0, 0);
        }
    }
#pragma unroll
    for (int s = 0; s < 2; ++s)
#pragma unroll
        for (int v = 0; v < 4; ++v) {
            const int row = wrow + s * 16 + q * 4 + v;
            if (row < nrows) {
#pragma unroll
                for (int c = 0; c < 8; ++c)
                    Out[(size_t)row * 128 + c * 16 + r] = f2bf(acc[s][c][v]);
            }
        }
}

// --------------------------- Aggregation -----------------------------------
// One wave per node; lane l owns features 2l, 2l+1 (one packed uint of 2 bf16).
// acc = dinv_i * ( sum_{src in-edges} xw[src]*dinv[src] + xw[i]*dinv_i )

__global__ __launch_bounds__(256)
void agg1_kernel(const unsigned short* __restrict__ xw, const int* __restrict__ colv,
                 const int* __restrict__ rowp, const float* __restrict__ dinv,
                 const float* __restrict__ b1, const float* __restrict__ Wc,
                 const float* __restrict__ bc, unsigned short* __restrict__ h1,
                 float* __restrict__ outp, int n) {
    const int node = blockIdx.x * 4 + (threadIdx.x >> 6);
    if (node >= n) return;
    const int lane = threadIdx.x & 63;
    const float di = dinv[node];
    const unsigned int* xrow = reinterpret_cast<const unsigned int*>(xw);

    unsigned int u = xrow[(size_t)node * 64 + lane];
    float acc0 = bflo(u) * di;
    float acc1 = bfhi(u) * di;

    const int beg = rowp[node], end = rowp[node + 1];
    for (int base = beg; base < end; base += 64) {
        const int e = base + lane;
        int s = 0; float w = 0.f;
        if (e < end) { s = colv[e]; w = dinv[s]; }
        const int cnt = min(64, end - base);
#pragma unroll 2
        for (int t = 0; t < cnt; ++t) {
            const int   st = __shfl(s, t);
            const float wt = __shfl(w, t);
            const unsigned int uu = xrow[(size_t)st * 64 + lane];
            acc0 += bflo(uu) * wt;
            acc1 += bfhi(uu) * wt;
        }
    }
    acc0 = fmaxf(acc0 * di + b1[2 * lane], 0.f);
    acc1 = fmaxf(acc1 * di + b1[2 * lane + 1], 0.f);

    reinterpret_cast<unsigned int*>(h1)[(size_t)node * 64 + lane] =
        (unsigned int)f2bf(acc0) | ((unsigned int)f2bf(acc1) << 16);

    // logits_coarse = h1 @ Wc + bc  (Wc: 128x2 row-major)
    float c0 = acc0 * Wc[4 * lane]     + acc1 * Wc[4 * lane + 2];
    float c1 = acc0 * Wc[4 * lane + 1] + acc1 * Wc[4 * lane + 3];
#pragma unroll
    for (int off = 32; off; off >>= 1) {
        c0 += __shfl_down(c0, off);
        c1 += __shfl_down(c1, off);
    }
    if (lane == 0) {
        outp[2 * (size_t)node]     = 0.5f * (c0 + bc[0]);
        outp[2 * (size_t)node + 1] = 0.5f * (c1 + bc[1]);
    }
}

__global__ __launch_bounds__(256)
void agg2_kernel(const unsigned short* __restrict__ xw2, const unsigned short* __restrict__ h1,
                 const int* __restrict__ colv, const int* __restrict__ rowp,
                 const float* __restrict__ dinv, const float* __restrict__ b2,
                 const float* __restrict__ Wf, const float* __restrict__ bfv,
                 const float* __restrict__ hnode, float* __restrict__ outp, int n) {
    const int node = blockIdx.x * 4 + (threadIdx.x >> 6);
    if (node >= n) return;
    const int lane = threadIdx.x & 63;
    const float di = dinv[node];
    const unsigned int* xrow = reinterpret_cast<const unsigned int*>(xw2);

    unsigned int u = xrow[(size_t)node * 64 + lane];
    float acc0 = bflo(u) * di;
    float acc1 = bfhi(u) * di;

    const int beg = rowp[node], end = rowp[node + 1];
    for (int base = beg; base < end; base += 64) {
        const int e = base + lane;
        int s = 0; float w = 0.f;
        if (e < end) { s = colv[e]; w = dinv[s]; }
        const int cnt = min(64, end - base);
#pragma unroll 2
        for (int t = 0; t < cnt; ++t) {
            const int   st = __shfl(s, t);
            const float wt = __shfl(w, t);
            const unsigned int uu = xrow[(size_t)st * 64 + lane];
            acc0 += bflo(uu) * wt;
            acc1 += bfhi(uu) * wt;
        }
    }
    float h20 = fmaxf(acc0 * di + b2[2 * lane], 0.f);
    float h21 = fmaxf(acc1 * di + b2[2 * lane + 1], 0.f);

    const float alpha = hnode[node];
    const unsigned int hu = reinterpret_cast<const unsigned int*>(h1)[(size_t)node * 64 + lane];
    const float ha0 = alpha * h20 + (1.f - alpha) * bflo(hu);
    const float ha1 = alpha * h21 + (1.f - alpha) * bfhi(hu);

    float f0 = ha0 * Wf[4 * lane]     + ha1 * Wf[4 * lane + 2];
    float f1 = ha0 * Wf[4 * lane + 1] + ha1 * Wf[4 * lane + 3];
#pragma unroll
    for (int off = 32; off; off >>= 1) {
        f0 += __shfl_down(f0, off);
        f1 += __shfl_down(f1, off);
    }
    if (lane == 0) {
        outp[2 * (size_t)node]     += 0.5f * (f0 + bfv[0]);
        outp[2 * (size_t)node + 1] += 0.5f * (f1 + bfv[1]);
    }
}

// ------------------------------ launch -------------------------------------

extern "C" void kernel_launch(void* const* d_in, const int* in_sizes, int n_in,
                              void* d_out, int out_size, void* d_ws, size_t ws_size,
                              hipStream_t stream) {
    const float* x     = (const float*)d_in[0];
    const int*   ei    = (const int*)d_in[1];     // int32 per harness contract
    const float* hnode = (const float*)d_in[2];
    const float* W1    = (const float*)d_in[3];
    const float* b1    = (const float*)d_in[4];
    const float* W2    = (const float*)d_in[5];
    const float* b2    = (const float*)d_in[6];
    const float* Wc    = (const float*)d_in[7];
    const float* bc    = (const float*)d_in[8];
    const float* Wf    = (const float*)d_in[9];
    const float* bfv   = (const float*)d_in[10];

    const int N  = in_sizes[2];
    const int E  = in_sizes[1] / 2;
    const int K1 = in_sizes[3] / HID;   // 256
    const int* srcv = ei;
    const int* dstv = ei + E;
    float* outp = (float*)d_out;

    char* ws = (char*)d_ws;
    size_t off = 0;
    auto alloc = [&](size_t bytes) -> char* {
        char* p = ws + off;
        off += (bytes + 255) & ~(size_t)255;
        return p;
    };
    unsigned short* xw      = (unsigned short*)alloc((size_t)N * HID * 2);  // 25.6 MB
    unsigned short* h1      = (unsigned short*)alloc((size_t)N * HID * 2);  // 25.6 MB
    float*          dinv    = (float*)alloc((size_t)N * 4);
    int*            counts  = (int*)alloc((size_t)N * 4);
    int*            rowp    = (int*)alloc((size_t)(N + 1) * 4);
    int*            rowcur  = (int*)alloc((size_t)N * 4);
    int*            colv    = (int*)alloc((size_t)E * 4);                   // 6.4 MB
    int*            partials= (int*)alloc(4096);
    unsigned short* wt1     = (unsigned short*)alloc((size_t)HID * K1 * 2);
    unsigned short* wt2     = (unsigned short*)alloc((size_t)HID * HID * 2);

    hipMemsetAsync(counts, 0, (size_t)N * 4, stream);
    wtprep_kernel<<<(HID * K1 + 255) / 256, 256, 0, stream>>>(W1, wt1, K1);
    wtprep_kernel<<<(HID * HID + 255) / 256, 256, 0, stream>>>(W2, wt2, HID);
    hist_kernel<<<(E + 255) / 256, 256, 0, stream>>>(dstv, counts, E, N);
    dinv_kernel<<<(N + 255) / 256, 256, 0, stream>>>(counts, dinv, N);

    const int nchunks = (N + 1023) / 1024;
    scan1_kernel<<<nchunks, 256, 0, stream>>>(counts, rowp + 1, partials, N);
    scan2_kernel<<<1, 64, 0, stream>>>(partials, nchunks);
    scan3_kernel<<<(N + 255) / 256, 256, 0, stream>>>(rowp, partials, N);
    rowcur_kernel<<<(N + 255) / 256, 256, 0, stream>>>(rowp, rowcur, N);
    fill_kernel<<<(E + 255) / 256, 256, 0, stream>>>(srcv, dstv, rowcur, colv, E, N);

    gemm_kernel<false><<<(N + 127) / 128, 256, 0, stream>>>((const void*)x, wt1, xw, N, K1);
    agg1_kernel<<<(N + 3) / 4, 256, 0, stream>>>(xw, colv, rowp, dinv, b1, Wc, bc, h1, outp, N);
    gemm_kernel<true><<<(N + 127) / 128, 256, 0, stream>>>((const void*)h1, wt2, xw, N, HID);
    agg2_kernel<<<(N + 3) / 4, 256, 0, stream>>>(xw, h1, colv, rowp, dinv, b2, Wf, bfv, hnode, outp, N);
}

// Round 3
// 545.904 us; speedup vs baseline: 1.2185x; 1.2185x over previous
//
#include <hip/hip_runtime.h>

// ---------------------------------------------------------------------------
// GCN 2-layer fused pipeline for MI355X (gfx950)
//   h1 = relu(Dinv (A+I) Dinv (x@W1) + b1)
//   out = 0.5*(h1@Wc + bc) + 0.5*((alpha*h2 + (1-alpha)*h1)@Wf + bf)
//   h2 = relu(Dinv (A+I) Dinv (h1@W2) + b2)
// R2: replaced scattered-atomic hist/fill (106MB write amplification, 142us)
// with locality-binned two-pass counting sort: bincount -> binscan -> stage
// (LDS block-binning, packed 4B pairs) -> nodecount (LDS) -> fine (per-bin
// LDS rowcur, colv scatter confined to one CU's L2 region).
// ---------------------------------------------------------------------------

#define HID 128
#define SHIFT 9
#define RANGE 512           // nodes per bin = 1<<SHIFT
#define MAXB 256            // max bins (N <= 131072)
#define TILE 4096           // edges per stage block

typedef __bf16 bf16x8 __attribute__((ext_vector_type(8)));
typedef float  f32x4  __attribute__((ext_vector_type(4)));

__device__ __forceinline__ unsigned short f2bf(float x) {
    unsigned int b = __float_as_uint(x);
    b += 0x7fffu + ((b >> 16) & 1u);     // round-to-nearest-even
    return (unsigned short)(b >> 16);
}
__device__ __forceinline__ float bflo(unsigned int u) { return __uint_as_float(u << 16); }
__device__ __forceinline__ float bfhi(unsigned int u) { return __uint_as_float(u & 0xffff0000u); }

// --------------------------- binned CSR build ------------------------------

__global__ __launch_bounds__(256)
void bincount_kernel(const int* __restrict__ dst, int* __restrict__ bin_counts,
                     int E, int NB) {
    __shared__ int h[MAXB];
    for (int i = threadIdx.x; i < NB; i += 256) h[i] = 0;
    __syncthreads();
    const int base = blockIdx.x * TILE;
#pragma unroll
    for (int j = 0; j < TILE; j += 256) {
        int e = base + j + threadIdx.x;
        if (e < E) atomicAdd(&h[((unsigned)dst[e]) >> SHIFT], 1);
    }
    __syncthreads();
    for (int i = threadIdx.x; i < NB; i += 256) {
        int v = h[i];
        if (v) atomicAdd(&bin_counts[i], v);
    }
}

__global__ void binscan_kernel(const int* __restrict__ bin_counts,
                               int* __restrict__ bin_off, int* __restrict__ bin_cur, int NB) {
    __shared__ int sh[MAXB];
    const int t = threadIdx.x;
    int v = (t < NB) ? bin_counts[t] : 0;
    sh[t] = v;
    __syncthreads();
    for (int s = 1; s < 256; s <<= 1) {
        int x = (t >= s) ? sh[t - s] : 0;
        __syncthreads();
        sh[t] += x;
        __syncthreads();
    }
    if (t < NB) {
        int ex = sh[t] - v;     // exclusive
        bin_off[t] = ex;
        bin_cur[t] = ex;
    }
}

// Block-level binning: tile-local LDS sort by bin, then bin-sorted write-out
// in contiguous runs. pairs[i] = (dlocal<<23) | src   (src < 2^23).
__global__ __launch_bounds__(256)
void stage_kernel(const int* __restrict__ src, const int* __restrict__ dst,
                  int* __restrict__ bin_cur, unsigned* __restrict__ pairs, int E) {
    __shared__ int sh_hist[MAXB];
    __shared__ int sh_off[MAXB];
    __shared__ int sh_ex[MAXB];
    __shared__ int sh_gbase[MAXB];
    __shared__ uint2 stg[TILE];
    const int t = threadIdx.x;
    const int base = blockIdx.x * TILE;
    const int cnt = min(TILE, E - base);

    for (int i = t; i < MAXB; i += 256) sh_hist[i] = 0;
    __syncthreads();

    int s[16], d[16], r[16];
#pragma unroll
    for (int j = 0; j < 16; ++j) {
        const int k = j * 256 + t;
        if (k < cnt) {
            s[j] = src[base + k];
            d[j] = dst[base + k];
            r[j] = atomicAdd(&sh_hist[((unsigned)d[j]) >> SHIFT], 1);
        }
    }
    __syncthreads();

    const int hv = sh_hist[t];
    sh_off[t] = hv;
    __syncthreads();
    for (int st = 1; st < 256; st <<= 1) {
        int x = (t >= st) ? sh_off[t - st] : 0;
        __syncthreads();
        sh_off[t] += x;
        __syncthreads();
    }
    sh_ex[t] = sh_off[t] - hv;                      // exclusive within tile
    if (hv > 0) sh_gbase[t] = atomicAdd(&bin_cur[t], hv);
    __syncthreads();

#pragma unroll
    for (int j = 0; j < 16; ++j) {
        const int k = j * 256 + t;
        if (k < cnt) {
            int b = ((unsigned)d[j]) >> SHIFT;
            stg[sh_ex[b] + r[j]] = make_uint2((unsigned)s[j], (unsigned)d[j]);
        }
    }
    __syncthreads();

    for (int i = t; i < cnt; i += 256) {
        uint2 p = stg[i];
        int b = (int)(p.y >> SHIFT);
        unsigned w = ((p.y & (RANGE - 1)) << 23) | p.x;
        pairs[sh_gbase[b] + (i - sh_ex[b])] = w;
    }
}

// Per-bin node in-degree counts via LDS (replaces scattered-atomic hist)
__global__ __launch_bounds__(256)
void nodecount_kernel(const unsigned* __restrict__ pairs, const int* __restrict__ bin_off,
                      int* __restrict__ counts, int N, int NB, int E) {
    __shared__ int c[RANGE];
    const int b = blockIdx.x;
    const int nb = b << SHIFT;
    const int nr = min(RANGE, N - nb);
    for (int i = threadIdx.x; i < nr; i += 256) c[i] = 0;
    __syncthreads();
    const int lo = bin_off[b];
    const int hi = (b + 1 < NB) ? bin_off[b + 1] : E;
    for (int i = lo + threadIdx.x; i < hi; i += 256)
        atomicAdd(&c[pairs[i] >> 23], 1);
    __syncthreads();
    for (int i = threadIdx.x; i < nr; i += 256) counts[nb + i] = c[i];
}

// Per-bin fine scatter: colv writes confined to this bin's contiguous region
__global__ __launch_bounds__(256)
void fine_kernel(const unsigned* __restrict__ pairs, const int* __restrict__ bin_off,
                 const int* __restrict__ rowp, int* __restrict__ colv,
                 int N, int NB, int E) {
    __shared__ int cur[RANGE];
    const int b = blockIdx.x;
    const int nb = b << SHIFT;
    const int nr = min(RANGE, N - nb);
    for (int i = threadIdx.x; i < nr; i += 256) cur[i] = rowp[nb + i];
    __syncthreads();
    const int lo = bin_off[b];
    const int hi = (b + 1 < NB) ? bin_off[b + 1] : E;
    for (int i = lo + threadIdx.x; i < hi; i += 256) {
        unsigned w = pairs[i];
        int pos = atomicAdd(&cur[w >> 23], 1);
        colv[pos] = (int)(w & 0x7fffffu);
    }
}

// ----------------------- degree / scan (unchanged) -------------------------

__global__ void dinv_kernel(const int* __restrict__ counts, float* __restrict__ dinv, int n) {
    int i = blockIdx.x * 256 + threadIdx.x;
    if (i < n) dinv[i] = rsqrtf((float)(counts[i] + 1));   // +1 self-loop
}

__global__ __launch_bounds__(256)
void scan1_kernel(const int* __restrict__ counts, int* __restrict__ rowp1,
                  int* __restrict__ partials, int n) {
    __shared__ int sh[256];
    const int t = threadIdx.x;
    const int base = blockIdx.x * 1024 + t * 4;
    int v0 = (base     < n) ? counts[base]     : 0;
    int v1 = (base + 1 < n) ? counts[base + 1] : 0;
    int v2 = (base + 2 < n) ? counts[base + 2] : 0;
    int v3 = (base + 3 < n) ? counts[base + 3] : 0;
    v1 += v0; v2 += v1; v3 += v2;
    sh[t] = v3;
    __syncthreads();
    for (int off = 1; off < 256; off <<= 1) {
        int x = (t >= off) ? sh[t - off] : 0;
        __syncthreads();
        sh[t] += x;
        __syncthreads();
    }
    const int prefix = sh[t] - v3;
    if (base     < n) rowp1[base]     = prefix + v0;
    if (base + 1 < n) rowp1[base + 1] = prefix + v1;
    if (base + 2 < n) rowp1[base + 2] = prefix + v2;
    if (base + 3 < n) rowp1[base + 3] = prefix + v3;
    if (t == 255) partials[blockIdx.x] = sh[255];
}

__global__ void scan2_kernel(int* partials, int nchunks) {
    if (threadIdx.x == 0 && blockIdx.x == 0) {
        int run = 0;
        for (int i = 0; i < nchunks; ++i) { int t = partials[i]; partials[i] = run; run += t; }
    }
}

__global__ void scan3_kernel(int* __restrict__ rowp, const int* __restrict__ partials, int n) {
    int i = blockIdx.x * 256 + threadIdx.x;
    if (i < n) rowp[1 + i] += partials[i >> 10];
    if (i == 0) rowp[0] = 0;
}

// W (K x 128, row-major fp32) -> Wt (128 x K, bf16)
__global__ void wtprep_kernel(const float* __restrict__ W, unsigned short* __restrict__ Wt, int K) {
    int idx = blockIdx.x * 256 + threadIdx.x;
    if (idx < 128 * K) {
        int nn = idx / K, k = idx - nn * K;
        Wt[(size_t)nn * K + k] = f2bf(W[(size_t)k * 128 + nn]);
    }
}

// ------------------------------- GEMM --------------------------------------
template <bool A_BF16>
__global__ __launch_bounds__(256)
void gemm_kernel(const void* __restrict__ Aptr, const unsigned short* __restrict__ Wt,
                 unsigned short* __restrict__ Out, int nrows, int K) {
    const int tid  = threadIdx.x;
    const int wave = tid >> 6;
    const int lane = tid & 63;
    const int q = lane >> 4;
    const int r = lane & 15;
    const int wrow = blockIdx.x * 128 + wave * 32;

    f32x4 acc[2][8];
#pragma unroll
    for (int s = 0; s < 2; ++s)
#pragma unroll
        for (int c = 0; c < 8; ++c) acc[s][c] = (f32x4){0.f, 0.f, 0.f, 0.f};

    for (int k0 = 0; k0 < K; k0 += 32) {
        const int kk = k0 + q * 8;
        bf16x8 afrag[2];
#pragma unroll
        for (int s = 0; s < 2; ++s) {
            const int row = wrow + s * 16 + r;
            if (row < nrows) {
                if (A_BF16) {
                    afrag[s] = *reinterpret_cast<const bf16x8*>(
                        reinterpret_cast<const unsigned short*>(Aptr) + (size_t)row * K + kk);
                } else {
                    const float* ap = reinterpret_cast<const float*>(Aptr) + (size_t)row * K + kk;
                    const float4 x0 = *reinterpret_cast<const float4*>(ap);
                    const float4 x1 = *reinterpret_cast<const float4*>(ap + 4);
                    bf16x8 a;
                    a[0] = (__bf16)x0.x; a[1] = (__bf16)x0.y; a[2] = (__bf16)x0.z; a[3] = (__bf16)x0.w;
                    a[4] = (__bf16)x1.x; a[5] = (__bf16)x1.y; a[6] = (__bf16)x1.z; a[7] = (__bf16)x1.w;
                    afrag[s] = a;
                }
            } else {
                bf16x8 a;
#pragma unroll
                for (int j = 0; j < 8; ++j) a[j] = (__bf16)0.f;
                afrag[s] = a;
            }
        }
#pragma unroll
        for (int c = 0; c < 8; ++c) {
            const bf16x8 b = *reinterpret_cast<const bf16x8*>(Wt + (size_t)(c * 16 + r) * K + kk);
#pragma unroll
            for (int s = 0; s < 2; ++s)
                acc[s][c] = __builtin_amdgcn_mfma_f32_16x16x32_bf16(afrag[s], b, acc[s][c], 0, 0, 0);
        }
    }
#pragma unroll
    for (int s = 0; s < 2; ++s)
#pragma unroll
        for (int v = 0; v < 4; ++v) {
            const int row = wrow + s * 16 + q * 4 + v;
            if (row < nrows) {
#pragma unroll
                for (int c = 0; c < 8; ++c)
                    Out[(size_t)row * 128 + c * 16 + r] = f2bf(acc[s][c][v]);
            }
        }
}

// --------------------------- Aggregation -----------------------------------

__global__ __launch_bounds__(256)
void agg1_kernel(const unsigned short* __restrict__ xw, const int* __restrict__ colv,
                 const int* __restrict__ rowp, const float* __restrict__ dinv,
                 const float* __restrict__ b1, const float* __restrict__ Wc,
                 const float* __restrict__ bc, unsigned short* __restrict__ h1,
                 float* __restrict__ outp, int n) {
    const int node = blockIdx.x * 4 + (threadIdx.x >> 6);
    if (node >= n) return;
    const int lane = threadIdx.x & 63;
    const float di = dinv[node];
    const unsigned int* xrow = reinterpret_cast<const unsigned int*>(xw);

    unsigned int u = xrow[(size_t)node * 64 + lane];
    float acc0 = bflo(u) * di;
    float acc1 = bfhi(u) * di;

    const int beg = rowp[node], end = rowp[node + 1];
    for (int base = beg; base < end; base += 64) {
        const int e = base + lane;
        int s = 0; float w = 0.f;
        if (e < end) { s = colv[e]; w = dinv[s]; }
        const int cnt = min(64, end - base);
#pragma unroll 2
        for (int t = 0; t < cnt; ++t) {
            const int   st = __shfl(s, t);
            const float wt = __shfl(w, t);
            const unsigned int uu = xrow[(size_t)st * 64 + lane];
            acc0 += bflo(uu) * wt;
            acc1 += bfhi(uu) * wt;
        }
    }
    acc0 = fmaxf(acc0 * di + b1[2 * lane], 0.f);
    acc1 = fmaxf(acc1 * di + b1[2 * lane + 1], 0.f);

    reinterpret_cast<unsigned int*>(h1)[(size_t)node * 64 + lane] =
        (unsigned int)f2bf(acc0) | ((unsigned int)f2bf(acc1) << 16);

    float c0 = acc0 * Wc[4 * lane]     + acc1 * Wc[4 * lane + 2];
    float c1 = acc0 * Wc[4 * lane + 1] + acc1 * Wc[4 * lane + 3];
#pragma unroll
    for (int off = 32; off; off >>= 1) {
        c0 += __shfl_down(c0, off);
        c1 += __shfl_down(c1, off);
    }
    if (lane == 0) {
        outp[2 * (size_t)node]     = 0.5f * (c0 + bc[0]);
        outp[2 * (size_t)node + 1] = 0.5f * (c1 + bc[1]);
    }
}

__global__ __launch_bounds__(256)
void agg2_kernel(const unsigned short* __restrict__ xw2, const unsigned short* __restrict__ h1,
                 const int* __restrict__ colv, const int* __restrict__ rowp,
                 const float* __restrict__ dinv, const float* __restrict__ b2,
                 const float* __restrict__ Wf, const float* __restrict__ bfv,
                 const float* __restrict__ hnode, float* __restrict__ outp, int n) {
    const int node = blockIdx.x * 4 + (threadIdx.x >> 6);
    if (node >= n) return;
    const int lane = threadIdx.x & 63;
    const float di = dinv[node];
    const unsigned int* xrow = reinterpret_cast<const unsigned int*>(xw2);

    unsigned int u = xrow[(size_t)node * 64 + lane];
    float acc0 = bflo(u) * di;
    float acc1 = bfhi(u) * di;

    const int beg = rowp[node], end = rowp[node + 1];
    for (int base = beg; base < end; base += 64) {
        const int e = base + lane;
        int s = 0; float w = 0.f;
        if (e < end) { s = colv[e]; w = dinv[s]; }
        const int cnt = min(64, end - base);
#pragma unroll 2
        for (int t = 0; t < cnt; ++t) {
            const int   st = __shfl(s, t);
            const float wt = __shfl(w, t);
            const unsigned int uu = xrow[(size_t)st * 64 + lane];
            acc0 += bflo(uu) * wt;
            acc1 += bfhi(uu) * wt;
        }
    }
    float h20 = fmaxf(acc0 * di + b2[2 * lane], 0.f);
    float h21 = fmaxf(acc1 * di + b2[2 * lane + 1], 0.f);

    const float alpha = hnode[node];
    const unsigned int hu = reinterpret_cast<const unsigned int*>(h1)[(size_t)node * 64 + lane];
    const float ha0 = alpha * h20 + (1.f - alpha) * bflo(hu);
    const float ha1 = alpha * h21 + (1.f - alpha) * bfhi(hu);

    float f0 = ha0 * Wf[4 * lane]     + ha1 * Wf[4 * lane + 2];
    float f1 = ha0 * Wf[4 * lane + 1] + ha1 * Wf[4 * lane + 3];
#pragma unroll
    for (int off = 32; off; off >>= 1) {
        f0 += __shfl_down(f0, off);
        f1 += __shfl_down(f1, off);
    }
    if (lane == 0) {
        outp[2 * (size_t)node]     += 0.5f * (f0 + bfv[0]);
        outp[2 * (size_t)node + 1] += 0.5f * (f1 + bfv[1]);
    }
}

// ------------------------------ launch -------------------------------------

extern "C" void kernel_launch(void* const* d_in, const int* in_sizes, int n_in,
                              void* d_out, int out_size, void* d_ws, size_t ws_size,
                              hipStream_t stream) {
    const float* x     = (const float*)d_in[0];
    const int*   ei    = (const int*)d_in[1];     // int32 per harness contract
    const float* hnode = (const float*)d_in[2];
    const float* W1    = (const float*)d_in[3];
    const float* b1    = (const float*)d_in[4];
    const float* W2    = (const float*)d_in[5];
    const float* b2    = (const float*)d_in[6];
    const float* Wc    = (const float*)d_in[7];
    const float* bc    = (const float*)d_in[8];
    const float* Wf    = (const float*)d_in[9];
    const float* bfv   = (const float*)d_in[10];

    const int N  = in_sizes[2];
    const int E  = in_sizes[1] / 2;
    const int K1 = in_sizes[3] / HID;   // 256
    const int NB = (N + RANGE - 1) >> SHIFT;
    const int* srcv = ei;
    const int* dstv = ei + E;
    float* outp = (float*)d_out;

    char* ws = (char*)d_ws;
    size_t off = 0;
    auto alloc = [&](size_t bytes) -> char* {
        char* p = ws + off;
        off += (bytes + 255) & ~(size_t)255;
        return p;
    };
    unsigned short* xw       = (unsigned short*)alloc((size_t)N * HID * 2);  // 25.6 MB
    unsigned short* h1       = (unsigned short*)alloc((size_t)N * HID * 2);  // 25.6 MB
    float*          dinv     = (float*)alloc((size_t)N * 4);
    int*            counts   = (int*)alloc((size_t)N * 4);
    int*            rowp     = (int*)alloc((size_t)(N + 1) * 4);
    int*            colv     = (int*)alloc((size_t)E * 4);                   // 6.4 MB
    unsigned*       pairs    = (unsigned*)alloc((size_t)E * 4);              // 6.4 MB
    int*            bin_counts = (int*)alloc(MAXB * 4);
    int*            bin_off    = (int*)alloc(MAXB * 4);
    int*            bin_cur    = (int*)alloc(MAXB * 4);
    int*            partials   = (int*)alloc(4096);
    unsigned short* wt1      = (unsigned short*)alloc((size_t)HID * K1 * 2);
    unsigned short* wt2      = (unsigned short*)alloc((size_t)HID * HID * 2);

    hipMemsetAsync(bin_counts, 0, MAXB * 4, stream);
    wtprep_kernel<<<(HID * K1 + 255) / 256, 256, 0, stream>>>(W1, wt1, K1);
    wtprep_kernel<<<(HID * HID + 255) / 256, 256, 0, stream>>>(W2, wt2, HID);

    const int ntiles = (E + TILE - 1) / TILE;
    bincount_kernel<<<ntiles, 256, 0, stream>>>(dstv, bin_counts, E, NB);
    binscan_kernel<<<1, 256, 0, stream>>>(bin_counts, bin_off, bin_cur, NB);
    stage_kernel<<<ntiles, 256, 0, stream>>>(srcv, dstv, bin_cur, pairs, E);
    nodecount_kernel<<<NB, 256, 0, stream>>>(pairs, bin_off, counts, N, NB, E);
    dinv_kernel<<<(N + 255) / 256, 256, 0, stream>>>(counts, dinv, N);

    const int nchunks = (N + 1023) / 1024;
    scan1_kernel<<<nchunks, 256, 0, stream>>>(counts, rowp + 1, partials, N);
    scan2_kernel<<<1, 64, 0, stream>>>(partials, nchunks);
    scan3_kernel<<<(N + 255) / 256, 256, 0, stream>>>(rowp, partials, N);
    fine_kernel<<<NB, 256, 0, stream>>>(pairs, bin_off, rowp, colv, N, NB, E);

    gemm_kernel<false><<<(N + 127) / 128, 256, 0, stream>>>((const void*)x, wt1, xw, N, K1);
    agg1_kernel<<<(N + 3) / 4, 256, 0, stream>>>(xw, colv, rowp, dinv, b1, Wc, bc, h1, outp, N);
    gemm_kernel<true><<<(N + 127) / 128, 256, 0, stream>>>((const void*)h1, wt2, xw, N, HID);
    agg2_kernel<<<(N + 3) / 4, 256, 0, stream>>>(xw, h1, colv, rowp, dinv, b2, Wf, bfv, hnode, outp, N);
}